// Round 1
// baseline (37795.972 us; speedup 1.0000x reference)
//
#include <hip/hip_runtime.h>

#define HD 512
#define BB 1024
#define TT 512
#define PP 96
#define DIN 32

typedef __attribute__((ext_vector_type(8))) short bf16x8;
typedef __attribute__((ext_vector_type(4))) float f32x4;

__device__ __forceinline__ float bf2f(unsigned short s) {
  return __uint_as_float(((unsigned)s) << 16);
}
__device__ __forceinline__ unsigned short f2bf_rne(float f) {
  unsigned u = __float_as_uint(f);
  u += 0x7FFF + ((u >> 16) & 1);
  return (unsigned short)(u >> 16);
}

// Pack fp32 weight matrix W[3H x K] (row-major, gate-major rows g*H+j) into
// MFMA B-fragment-linear bf16 hi/lo layout:
// linear group = ((((jb*KC + kc)*3 + g)*2 + s)*2 + fc)*64 + lane, 8 bf16/group.
// lane holds W[g*H + jb*32 + fc*16 + (lane&15)][kc*32 + (lane>>4)*8 + 0..7]
__global__ void pack_w_kernel(const float* __restrict__ W, int K,
                              unsigned short* __restrict__ out) {
  int tid = blockIdx.x * 256 + threadIdx.x;
  int KC = K >> 5;
  int total = 16 * KC * 3 * 2 * 2 * 64;
  if (tid >= total) return;
  int lane = tid & 63;
  int rest = tid >> 6;
  int fc = rest & 1; rest >>= 1;
  int s  = rest & 1; rest >>= 1;
  int g  = rest % 3; rest /= 3;
  int kc = rest % KC;
  int jb = rest / KC;
  int j = jb * 32 + fc * 16 + (lane & 15);
  int k = kc * 32 + (lane >> 4) * 8;
  const float* src = W + (size_t)(g * HD + j) * K + k;
  bf16x8 v;
#pragma unroll
  for (int i = 0; i < 8; ++i) {
    float f = src[i];
    unsigned short hi = f2bf_rne(f);
    v[i] = (short)((s == 0) ? hi : f2bf_rne(f - bf2f(hi)));
  }
  *(bf16x8*)(out + (size_t)tid * 8) = v;
}

// One GEMM phase: acc{R,Z,N} += split_bf16(A[rows x K]) @ packed W.
// 3-term hi/lo split => ~2^-16 relative accuracy (fp32-like).
__device__ __forceinline__ void mfma_phase(
    const float* __restrict__ A, int lda, int Kc,
    const unsigned short* __restrict__ Wp,
    int jblk, int row0, int lane,
    f32x4* __restrict__ aR, f32x4* __restrict__ aZ, f32x4* __restrict__ aN) {
  const int quad = lane >> 4, n16 = lane & 15;
  const float* ap = A + (size_t)(row0 + n16) * lda + quad * 8;
  const unsigned short* wp = Wp + (size_t)jblk * Kc * 6144 + lane * 8;
  for (int kc = 0; kc < Kc; ++kc) {
    f32x4 av0 = *(const f32x4*)ap;
    f32x4 av1 = *(const f32x4*)(ap + 4);
    bf16x8 ahi, alo;
#pragma unroll
    for (int i = 0; i < 8; ++i) {
      float f = (i < 4) ? av0[i] : av1[i - 4];
      unsigned u = __float_as_uint(f);
      unsigned short h = (unsigned short)(u >> 16);  // trunc split: lo corrects it
      ahi[i] = (short)h;
      float rem = f - bf2f(h);
      alo[i] = (short)(__float_as_uint(rem) >> 16);
    }
    ap += 32;
#pragma unroll
    for (int g = 0; g < 3; ++g) {
      f32x4* acc = (g == 0) ? aR : (g == 1) ? aZ : aN;
#pragma unroll
      for (int fc = 0; fc < 2; ++fc) {
        bf16x8 whi = *(const bf16x8*)(wp + g * 2048 + fc * 512);
        bf16x8 wlo = *(const bf16x8*)(wp + g * 2048 + 1024 + fc * 512);
        acc[fc] = __builtin_amdgcn_mfma_f32_16x16x32_bf16(ahi, whi, acc[fc], 0, 0, 0);
        acc[fc] = __builtin_amdgcn_mfma_f32_16x16x32_bf16(alo, whi, acc[fc], 0, 0, 0);
        acc[fc] = __builtin_amdgcn_mfma_f32_16x16x32_bf16(ahi, wlo, acc[fc], 0, 0, 0);
      }
    }
    wp += 6144;
  }
}

// Fused GRU step: [optional x-phase GEMM] + h-phase GEMM + gates + state update.
// Modes:
//   encoder L0/L1, dec L1: xA != nullptr (x-phase via MFMA)
//   dec L0: Wih0 != nullptr -> y from ypart_in (or dec_start at t=0), rank-1 gi,
//           writes previous step's y to dout
//   dec L1: ypart_out != nullptr -> per-jblk partial dot of h_new with outW
__global__ __launch_bounds__(256)
void gru_step_kernel(
    const float* __restrict__ xA, int ldx, int Kx, const unsigned short* __restrict__ WihP,
    const float* __restrict__ hA, const unsigned short* __restrict__ WhhP,
    const float* __restrict__ bih, const float* __restrict__ bhh,
    float* __restrict__ hout,
    const float* __restrict__ ypart_in, const float* __restrict__ outb,
    const float* __restrict__ dec_start, const float* __restrict__ Wih0,
    int tstep, float* __restrict__ dout,
    const float* __restrict__ outW, float* __restrict__ ypart_out) {
  const int jblk = blockIdx.x, rowblk = blockIdx.y;
  const int tid = threadIdx.x;
  const int wave = tid >> 6, lane = tid & 63;
  const int quad = lane >> 4, n16 = lane & 15;
  const int row0 = rowblk * 64 + wave * 16;

  f32x4 accR[2], accZ[2], accNX[2], accNH[2];
#pragma unroll
  for (int i = 0; i < 2; ++i)
#pragma unroll
    for (int r = 0; r < 4; ++r) {
      accR[i][r] = 0.f; accZ[i][r] = 0.f; accNX[i][r] = 0.f; accNH[i][r] = 0.f;
    }

  if (xA) mfma_phase(xA, ldx, Kx >> 5, WihP, jblk, row0, lane, accR, accZ, accNX);
  mfma_phase(hA, HD, HD >> 5, WhhP, jblk, row0, lane, accR, accZ, accNH);

  const bool decL0 = (Wih0 != nullptr);
  float yv[4] = {0.f, 0.f, 0.f, 0.f};
  if (decL0) {
#pragma unroll
    for (int reg = 0; reg < 4; ++reg) {
      int row = row0 + quad * 4 + reg;
      float s;
      if (tstep == 0) {
        s = dec_start[0];
      } else {
        s = outb[0];
#pragma unroll
        for (int p = 0; p < 16; ++p) s += ypart_in[p * BB + row];
      }
      yv[reg] = s;
      if (tstep > 0 && jblk == 0 && n16 == 0)
        dout[(size_t)row * PP + (tstep - 1)] = s;
    }
  }

  float hvv[2][4];
#pragma unroll
  for (int fc = 0; fc < 2; ++fc) {
    const int col = jblk * 32 + fc * 16 + n16;
    const float bir = bih[col],          bhr = bhh[col];
    const float biz = bih[HD + col],     bhz = bhh[HD + col];
    const float bin = bih[2 * HD + col], bhn = bhh[2 * HD + col];
    float w0r = 0.f, w0z = 0.f, w0n = 0.f;
    if (decL0) { w0r = Wih0[col]; w0z = Wih0[HD + col]; w0n = Wih0[2 * HD + col]; }
#pragma unroll
    for (int reg = 0; reg < 4; ++reg) {
      const int row = row0 + quad * 4 + reg;
      float sr = accR[fc][reg] + bir + bhr;
      float sz = accZ[fc][reg] + biz + bhz;
      float in_ = accNX[fc][reg] + bin;
      float hn = accNH[fc][reg] + bhn;
      if (decL0) { sr += yv[reg] * w0r; sz += yv[reg] * w0z; in_ += yv[reg] * w0n; }
      float r = 1.f / (1.f + __expf(-sr));
      float z = 1.f / (1.f + __expf(-sz));
      float a = in_ + r * hn;
      float nn = 1.f - 2.f / (__expf(2.f * a) + 1.f);  // tanh
      float ho = hA[(size_t)row * HD + col];
      float hv = (1.f - z) * nn + z * ho;
      hout[(size_t)row * HD + col] = hv;
      hvv[fc][reg] = hv;
    }
  }

  if (ypart_out) {
    const int col0 = jblk * 32 + n16;
    const float w0 = outW[col0], w1 = outW[col0 + 16];
#pragma unroll
    for (int reg = 0; reg < 4; ++reg) {
      float v = hvv[0][reg] * w0 + hvv[1][reg] * w1;
#pragma unroll
      for (int off = 1; off < 16; off <<= 1) v += __shfl_xor(v, off, 16);
      if (n16 == 0) ypart_out[jblk * BB + row0 + quad * 4 + reg] = v;
    }
  }
}

__global__ void finalize_y_kernel(const float* __restrict__ ypart,
                                  const float* __restrict__ outb,
                                  float* __restrict__ dout) {
  int b = blockIdx.x * 256 + threadIdx.x;
  if (b >= BB) return;
  float s = outb[0];
#pragma unroll
  for (int p = 0; p < 16; ++p) s += ypart[p * BB + b];
  dout[(size_t)b * PP + (PP - 1)] = s;
}

extern "C" void kernel_launch(void* const* d_in, const int* in_sizes, int n_in,
                              void* d_out, int out_size, void* d_ws, size_t ws_size,
                              hipStream_t stream) {
  const float* x      = (const float*)d_in[0];
  const float* eW_ih0 = (const float*)d_in[1];
  const float* eW_hh0 = (const float*)d_in[2];
  const float* eb_ih0 = (const float*)d_in[3];
  const float* eb_hh0 = (const float*)d_in[4];
  const float* eW_ih1 = (const float*)d_in[5];
  const float* eW_hh1 = (const float*)d_in[6];
  const float* eb_ih1 = (const float*)d_in[7];
  const float* eb_hh1 = (const float*)d_in[8];
  const float* dW_ih0 = (const float*)d_in[9];
  const float* dW_hh0 = (const float*)d_in[10];
  const float* db_ih0 = (const float*)d_in[11];
  const float* db_hh0 = (const float*)d_in[12];
  const float* dW_ih1 = (const float*)d_in[13];
  const float* dW_hh1 = (const float*)d_in[14];
  const float* db_ih1 = (const float*)d_in[15];
  const float* db_hh1 = (const float*)d_in[16];
  const float* outW   = (const float*)d_in[17];
  const float* outb   = (const float*)d_in[18];
  const float* dstart = (const float*)d_in[19];
  float* out = (float*)d_out;

  char* w = (char*)d_ws;
  size_t off = 0;
  auto carve = [&](size_t bytes) -> void* {
    void* p = w + off;
    off = (off + bytes + 255) & ~(size_t)255;
    return p;
  };
  float* h1a = (float*)carve((size_t)BB * HD * 4);
  float* h1b = (float*)carve((size_t)BB * HD * 4);
  float* h2a = (float*)carve((size_t)BB * HD * 4);
  float* h2b = (float*)carve((size_t)BB * HD * 4);
  float* ypart = (float*)carve((size_t)16 * BB * 4);
  auto carve_pack = [&](int K) -> unsigned short* {
    return (unsigned short*)carve((size_t)3 * HD * K * 2 * 2);
  };
  unsigned short* pk_e0ih = carve_pack(DIN);
  unsigned short* pk_e0hh = carve_pack(HD);
  unsigned short* pk_e1ih = carve_pack(HD);
  unsigned short* pk_e1hh = carve_pack(HD);
  unsigned short* pk_d0hh = carve_pack(HD);
  unsigned short* pk_d1ih = carve_pack(HD);
  unsigned short* pk_d1hh = carve_pack(HD);

  hipMemsetAsync(h1a, 0, (size_t)BB * HD * 4, stream);
  hipMemsetAsync(h2a, 0, (size_t)BB * HD * 4, stream);

  auto pack = [&](const float* W, int K, unsigned short* dst) {
    int total = 16 * (K >> 5) * 3 * 2 * 2 * 64;
    pack_w_kernel<<<(total + 255) / 256, 256, 0, stream>>>(W, K, dst);
  };
  pack(eW_ih0, DIN, pk_e0ih);
  pack(eW_hh0, HD, pk_e0hh);
  pack(eW_ih1, HD, pk_e1ih);
  pack(eW_hh1, HD, pk_e1hh);
  pack(dW_hh0, HD, pk_d0hh);
  pack(dW_ih1, HD, pk_d1ih);
  pack(dW_hh1, HD, pk_d1hh);

  dim3 grid(16, 16), blk(256);
  const float* cur1 = h1a; float* nxt1 = h1b;
  const float* cur2 = h2a; float* nxt2 = h2b;

  for (int t = 0; t < TT; ++t) {
    // encoder layer 0: x_t [B,32] + h1
    gru_step_kernel<<<grid, blk, 0, stream>>>(
        x + (size_t)t * DIN, TT * DIN, DIN, pk_e0ih, cur1, pk_e0hh,
        eb_ih0, eb_hh0, nxt1,
        nullptr, nullptr, nullptr, nullptr, 0, nullptr, nullptr, nullptr);
    // encoder layer 1: h1_new [B,512] + h2
    gru_step_kernel<<<grid, blk, 0, stream>>>(
        nxt1, HD, HD, pk_e1ih, cur2, pk_e1hh,
        eb_ih1, eb_hh1, nxt2,
        nullptr, nullptr, nullptr, nullptr, 0, nullptr, nullptr, nullptr);
    { const float* tmp = cur1; cur1 = nxt1; nxt1 = (float*)tmp; }
    { const float* tmp = cur2; cur2 = nxt2; nxt2 = (float*)tmp; }
  }

  for (int t = 0; t < PP; ++t) {
    // decoder layer 0: y (rank-1) + d1; also emits y_{t-1} to d_out
    gru_step_kernel<<<grid, blk, 0, stream>>>(
        nullptr, 0, 0, nullptr, cur1, pk_d0hh,
        db_ih0, db_hh0, nxt1,
        ypart, outb, dstart, dW_ih0, t, out, nullptr, nullptr);
    // decoder layer 1: d1_new + d2; emits ypart (partial dots with out_W)
    gru_step_kernel<<<grid, blk, 0, stream>>>(
        nxt1, HD, HD, pk_d1ih, cur2, pk_d1hh,
        db_ih1, db_hh1, nxt2,
        nullptr, nullptr, nullptr, nullptr, 0, nullptr, outW, ypart);
    { const float* tmp = cur1; cur1 = nxt1; nxt1 = (float*)tmp; }
    { const float* tmp = cur2; cur2 = nxt2; nxt2 = (float*)tmp; }
  }
  finalize_y_kernel<<<4, 256, 0, stream>>>(ypart, outb, out);
}

// Round 2
// 32486.786 us; speedup vs baseline: 1.1634x; 1.1634x over previous
//
#include <hip/hip_runtime.h>

#define HD 512
#define BB 1024
#define TT 512
#define PP 96
#define DIN 32
#define KC_H (HD / 32)  // 16

typedef unsigned short u16;
typedef __attribute__((ext_vector_type(8))) short bf16x8;
typedef __attribute__((ext_vector_type(4))) float f32x4;

__device__ __forceinline__ float bf2f(u16 s) {
  return __uint_as_float(((unsigned)s) << 16);
}
__device__ __forceinline__ u16 f2bf_rne(float f) {
  unsigned u = __float_as_uint(f);
  u += 0x7FFF + ((u >> 16) & 1);
  return (u16)(u >> 16);
}

// Pack fp32 weight W[3H x K] into MFMA B-frag-linear bf16 hi/lo layout.
// ushort offset = ((((jb*KC + kc)*3 + g)*2 + s)*2 + fc)*512 + lane*8
// lane holds W[g*H + jb*32 + fc*16 + (lane&15)][kc*32 + (lane>>4)*8 + 0..7]
__global__ void pack_w_kernel(const float* __restrict__ W, int K,
                              u16* __restrict__ out) {
  int tid = blockIdx.x * 256 + threadIdx.x;
  int KC = K >> 5;
  int total = 16 * KC * 3 * 2 * 2 * 64;
  if (tid >= total) return;
  int lane = tid & 63;
  int rest = tid >> 6;
  int fc = rest & 1; rest >>= 1;
  int s  = rest & 1; rest >>= 1;
  int g  = rest % 3; rest /= 3;
  int kc = rest % KC;
  int jb = rest / KC;
  int j = jb * 32 + fc * 16 + (lane & 15);
  int k = kc * 32 + (lane >> 4) * 8;
  const float* src = W + (size_t)(g * HD + j) * K + k;
  bf16x8 v;
#pragma unroll
  for (int i = 0; i < 8; ++i) {
    float f = src[i];
    u16 hi = f2bf_rne(f);
    v[i] = (short)((s == 0) ? hi : f2bf_rne(f - bf2f(hi)));
  }
  *(bf16x8*)(out + (size_t)tid * 8) = v;
}

// acc{R,Z,N} += split(A) @ Wslice, A given as pre-split bf16 hi/lo planes.
// 3-term split: ahi*whi + alo*whi + ahi*wlo  (~2^-16 rel accuracy).
__device__ __forceinline__ void mfma_phase_planes(
    const u16* __restrict__ Ahi, const u16* __restrict__ Alo,
    const u16* __restrict__ Wp, int jb, int fcsel,
    int row0, int lane, f32x4& aR, f32x4& aZ, f32x4& aN) {
  const int quad = lane >> 4, n16 = lane & 15;
  const u16* ah = Ahi + (size_t)(row0 + n16) * HD + quad * 8;
  const u16* al = Alo + (size_t)(row0 + n16) * HD + quad * 8;
  const u16* wp = Wp + (size_t)jb * KC_H * 6144 + fcsel * 512 + lane * 8;
#pragma unroll 2
  for (int kc = 0; kc < KC_H; ++kc) {
    bf16x8 ahi = *(const bf16x8*)ah;
    bf16x8 alo = *(const bf16x8*)al;
    ah += 32; al += 32;
#pragma unroll
    for (int g = 0; g < 3; ++g) {
      f32x4& acc = (g == 0) ? aR : (g == 1) ? aZ : aN;
      bf16x8 whi = *(const bf16x8*)(wp + g * 2048);
      bf16x8 wlo = *(const bf16x8*)(wp + g * 2048 + 1024);
      acc = __builtin_amdgcn_mfma_f32_16x16x32_bf16(ahi, whi, acc, 0, 0, 0);
      acc = __builtin_amdgcn_mfma_f32_16x16x32_bf16(alo, whi, acc, 0, 0, 0);
      acc = __builtin_amdgcn_mfma_f32_16x16x32_bf16(ahi, wlo, acc, 0, 0, 0);
    }
    wp += 6144;
  }
}

// x-phase for encoder L0: fp32 x[B,T,32], K=32 (one kc), inline split.
__device__ __forceinline__ void mfma_phase_x32(
    const float* __restrict__ x, int t, const u16* __restrict__ Wp,
    int jb, int fcsel, int row0, int lane, f32x4& aR, f32x4& aZ, f32x4& aN) {
  const int quad = lane >> 4, n16 = lane & 15;
  const float* xp = x + (size_t)(row0 + n16) * (TT * DIN) + (size_t)t * DIN + quad * 8;
  f32x4 v0 = *(const f32x4*)xp;
  f32x4 v1 = *(const f32x4*)(xp + 4);
  bf16x8 ahi, alo;
#pragma unroll
  for (int i = 0; i < 8; ++i) {
    float f = (i < 4) ? v0[i] : v1[i - 4];
    u16 h = (u16)(__float_as_uint(f) >> 16);
    ahi[i] = (short)h;
    alo[i] = (short)f2bf_rne(f - bf2f(h));
  }
  const u16* wp = Wp + (size_t)jb * 6144 + fcsel * 512 + lane * 8;
#pragma unroll
  for (int g = 0; g < 3; ++g) {
    f32x4& acc = (g == 0) ? aR : (g == 1) ? aZ : aN;
    bf16x8 whi = *(const bf16x8*)(wp + g * 2048);
    bf16x8 wlo = *(const bf16x8*)(wp + g * 2048 + 1024);
    acc = __builtin_amdgcn_mfma_f32_16x16x32_bf16(ahi, whi, acc, 0, 0, 0);
    acc = __builtin_amdgcn_mfma_f32_16x16x32_bf16(alo, whi, acc, 0, 0, 0);
    acc = __builtin_amdgcn_mfma_f32_16x16x32_bf16(ahi, wlo, acc, 0, 0, 0);
  }
}

__device__ __forceinline__ void split_store(u16* __restrict__ H, u16* __restrict__ L,
                                            size_t idx, float hv) {
  u16 hi = (u16)(__float_as_uint(hv) >> 16);  // trunc; lo corrects
  H[idx] = hi;
  L[idx] = f2bf_rne(hv - bf2f(hi));
}
__device__ __forceinline__ float plane_read(const u16* __restrict__ H,
                                            const u16* __restrict__ L, size_t idx) {
  return bf2f(H[idx]) + bf2f(L[idx]);
}
__device__ __forceinline__ float sigm(float v) { return 1.f / (1.f + __expf(-v)); }
__device__ __forceinline__ float tanh_(float a) {
  return 1.f - 2.f / (__expf(2.f * a) + 1.f);
}

// Fused (skewed) encoder phase: mode 0 = L0 only, 1 = L1 only, 2 = both.
// L0: h1next = cell0(x[t], h1cur).  L1: h2next = cell1(h1cur, h2cur)
// (h1cur is the output of L0 at step t-1 — exactly what L1(t-1) consumes).
__global__ __launch_bounds__(256, 4)
void enc_phase_kernel(int mode, int t, const float* __restrict__ x,
                      const u16* __restrict__ pkX0, const u16* __restrict__ pkH0,
                      const float* __restrict__ bi0, const float* __restrict__ bh0,
                      const u16* __restrict__ pkX1, const u16* __restrict__ pkH1,
                      const float* __restrict__ bi1, const float* __restrict__ bh1,
                      const u16* __restrict__ h1cH, const u16* __restrict__ h1cL,
                      u16* __restrict__ h1nH, u16* __restrict__ h1nL,
                      const u16* __restrict__ h2cH, const u16* __restrict__ h2cL,
                      u16* __restrict__ h2nH, u16* __restrict__ h2nL) {
  const int cx = blockIdx.x;
  const int layer = (mode == 2) ? (cx >= 32 ? 1 : 0) : mode;
  const int colblk = (mode == 2 && layer) ? cx - 32 : cx;
  const int jb = colblk >> 1, fcsel = colblk & 1;
  const int tid = threadIdx.x, wave = tid >> 6, lane = tid & 63;
  const int quad = lane >> 4, n16 = lane & 15;
  const int row0 = blockIdx.y * 64 + wave * 16;

  f32x4 aR = {0, 0, 0, 0}, aZ = {0, 0, 0, 0}, aNX = {0, 0, 0, 0}, aNH = {0, 0, 0, 0};

  const u16 *hcH, *hcL; u16 *hnH, *hnL;
  const float *bi, *bh;
  if (layer == 0) {
    mfma_phase_x32(x, t, pkX0, jb, fcsel, row0, lane, aR, aZ, aNX);
    mfma_phase_planes(h1cH, h1cL, pkH0, jb, fcsel, row0, lane, aR, aZ, aNH);
    hcH = h1cH; hcL = h1cL; hnH = h1nH; hnL = h1nL; bi = bi0; bh = bh0;
  } else {
    mfma_phase_planes(h1cH, h1cL, pkX1, jb, fcsel, row0, lane, aR, aZ, aNX);
    mfma_phase_planes(h2cH, h2cL, pkH1, jb, fcsel, row0, lane, aR, aZ, aNH);
    hcH = h2cH; hcL = h2cL; hnH = h2nH; hnL = h2nL; bi = bi1; bh = bh1;
  }

  const int col = colblk * 16 + n16;
  const float bir = bi[col],          bhr = bh[col];
  const float biz = bi[HD + col],     bhz = bh[HD + col];
  const float bin = bi[2 * HD + col], bhn = bh[2 * HD + col];
#pragma unroll
  for (int reg = 0; reg < 4; ++reg) {
    const int row = row0 + quad * 4 + reg;
    const size_t idx = (size_t)row * HD + col;
    float r = sigm(aR[reg] + bir + bhr);
    float z = sigm(aZ[reg] + biz + bhz);
    float nn = tanh_(aNX[reg] + bin + r * (aNH[reg] + bhn));
    float ho = plane_read(hcH, hcL, idx);
    split_store(hnH, hnL, idx, (1.f - z) * nn + z * ho);
  }
}

// Decoder L0: rank-1 gi from scalar y (reconstructed from ypart) + h-phase GEMM.
// Also writes y_{t-1} to dout.
__global__ __launch_bounds__(256, 4)
void dec_l0_kernel(int t, const float* __restrict__ ypart, const float* __restrict__ outb,
                   const float* __restrict__ dstart, const float* __restrict__ Wih0,
                   const u16* __restrict__ d1cH, const u16* __restrict__ d1cL,
                   const u16* __restrict__ pkHH,
                   const float* __restrict__ bih, const float* __restrict__ bhh,
                   u16* __restrict__ d1nH, u16* __restrict__ d1nL,
                   float* __restrict__ dout) {
  const int colblk = blockIdx.x;
  const int jb = colblk >> 1, fcsel = colblk & 1;
  const int tid = threadIdx.x, wave = tid >> 6, lane = tid & 63;
  const int quad = lane >> 4, n16 = lane & 15;
  const int row0 = blockIdx.y * 64 + wave * 16;

  f32x4 aR = {0, 0, 0, 0}, aZ = {0, 0, 0, 0}, aNH = {0, 0, 0, 0};
  mfma_phase_planes(d1cH, d1cL, pkHH, jb, fcsel, row0, lane, aR, aZ, aNH);

  float yv[4];
#pragma unroll
  for (int reg = 0; reg < 4; ++reg) {
    const int row = row0 + quad * 4 + reg;
    if (t == 0) {
      yv[reg] = dstart[0];
    } else {
      float s = outb[0];
#pragma unroll
      for (int p = 0; p < 32; ++p) s += ypart[p * BB + row];
      yv[reg] = s;
      if (colblk == 0 && n16 == 0) dout[(size_t)row * PP + (t - 1)] = s;
    }
  }

  const int col = colblk * 16 + n16;
  const float bir = bih[col],          bhr = bhh[col];
  const float biz = bih[HD + col],     bhz = bhh[HD + col];
  const float bin = bih[2 * HD + col], bhn = bhh[2 * HD + col];
  const float w0r = Wih0[col], w0z = Wih0[HD + col], w0n = Wih0[2 * HD + col];
#pragma unroll
  for (int reg = 0; reg < 4; ++reg) {
    const int row = row0 + quad * 4 + reg;
    const size_t idx = (size_t)row * HD + col;
    float r = sigm(aR[reg] + bir + bhr + yv[reg] * w0r);
    float z = sigm(aZ[reg] + biz + bhz + yv[reg] * w0z);
    float nn = tanh_(bin + yv[reg] * w0n + r * (aNH[reg] + bhn));
    float ho = plane_read(d1cH, d1cL, idx);
    split_store(d1nH, d1nL, idx, (1.f - z) * nn + z * ho);
  }
}

// Decoder L1: x-phase (d1 new) + h-phase (d2) GEMMs; emits ypart partial dots.
__global__ __launch_bounds__(256, 4)
void dec_l1_kernel(const u16* __restrict__ xH, const u16* __restrict__ xL,
                   const u16* __restrict__ pkIH,
                   const u16* __restrict__ d2cH, const u16* __restrict__ d2cL,
                   const u16* __restrict__ pkHH,
                   const float* __restrict__ bih, const float* __restrict__ bhh,
                   u16* __restrict__ d2nH, u16* __restrict__ d2nL,
                   const float* __restrict__ outW, float* __restrict__ ypart) {
  const int colblk = blockIdx.x;
  const int jb = colblk >> 1, fcsel = colblk & 1;
  const int tid = threadIdx.x, wave = tid >> 6, lane = tid & 63;
  const int quad = lane >> 4, n16 = lane & 15;
  const int row0 = blockIdx.y * 64 + wave * 16;

  f32x4 aR = {0, 0, 0, 0}, aZ = {0, 0, 0, 0}, aNX = {0, 0, 0, 0}, aNH = {0, 0, 0, 0};
  mfma_phase_planes(xH, xL, pkIH, jb, fcsel, row0, lane, aR, aZ, aNX);
  mfma_phase_planes(d2cH, d2cL, pkHH, jb, fcsel, row0, lane, aR, aZ, aNH);

  const int col = colblk * 16 + n16;
  const float bir = bih[col],          bhr = bhh[col];
  const float biz = bih[HD + col],     bhz = bhh[HD + col];
  const float bin = bih[2 * HD + col], bhn = bhh[2 * HD + col];
  const float wo = outW[col];
#pragma unroll
  for (int reg = 0; reg < 4; ++reg) {
    const int row = row0 + quad * 4 + reg;
    const size_t idx = (size_t)row * HD + col;
    float r = sigm(aR[reg] + bir + bhr);
    float z = sigm(aZ[reg] + biz + bhz);
    float nn = tanh_(aNX[reg] + bin + r * (aNH[reg] + bhn));
    float ho = plane_read(d2cH, d2cL, idx);
    float hv = (1.f - z) * nn + z * ho;
    split_store(d2nH, d2nL, idx, hv);
    float v = hv * wo;
#pragma unroll
    for (int off = 1; off < 16; off <<= 1) v += __shfl_xor(v, off, 16);
    if (n16 == 0) ypart[colblk * BB + row] = v;
  }
}

__global__ void finalize_y_kernel(const float* __restrict__ ypart,
                                  const float* __restrict__ outb,
                                  float* __restrict__ dout) {
  int b = blockIdx.x * 256 + threadIdx.x;
  if (b >= BB) return;
  float s = outb[0];
#pragma unroll
  for (int p = 0; p < 32; ++p) s += ypart[p * BB + b];
  dout[(size_t)b * PP + (PP - 1)] = s;
}

extern "C" void kernel_launch(void* const* d_in, const int* in_sizes, int n_in,
                              void* d_out, int out_size, void* d_ws, size_t ws_size,
                              hipStream_t stream) {
  const float* x      = (const float*)d_in[0];
  const float* eW_ih0 = (const float*)d_in[1];
  const float* eW_hh0 = (const float*)d_in[2];
  const float* eb_ih0 = (const float*)d_in[3];
  const float* eb_hh0 = (const float*)d_in[4];
  const float* eW_ih1 = (const float*)d_in[5];
  const float* eW_hh1 = (const float*)d_in[6];
  const float* eb_ih1 = (const float*)d_in[7];
  const float* eb_hh1 = (const float*)d_in[8];
  const float* dW_ih0 = (const float*)d_in[9];
  const float* dW_hh0 = (const float*)d_in[10];
  const float* db_ih0 = (const float*)d_in[11];
  const float* db_hh0 = (const float*)d_in[12];
  const float* dW_ih1 = (const float*)d_in[13];
  const float* dW_hh1 = (const float*)d_in[14];
  const float* db_ih1 = (const float*)d_in[15];
  const float* db_hh1 = (const float*)d_in[16];
  const float* outW   = (const float*)d_in[17];
  const float* outb   = (const float*)d_in[18];
  const float* dstart = (const float*)d_in[19];
  float* out = (float*)d_out;

  char* w = (char*)d_ws;
  size_t off = 0;
  auto carve = [&](size_t bytes) -> void* {
    void* p = w + off;
    off = (off + bytes + 255) & ~(size_t)255;
    return p;
  };
  u16* h1aH = (u16*)carve((size_t)BB * HD * 2); u16* h1aL = (u16*)carve((size_t)BB * HD * 2);
  u16* h1bH = (u16*)carve((size_t)BB * HD * 2); u16* h1bL = (u16*)carve((size_t)BB * HD * 2);
  u16* h2aH = (u16*)carve((size_t)BB * HD * 2); u16* h2aL = (u16*)carve((size_t)BB * HD * 2);
  u16* h2bH = (u16*)carve((size_t)BB * HD * 2); u16* h2bL = (u16*)carve((size_t)BB * HD * 2);
  float* ypart = (float*)carve((size_t)32 * BB * 4);
  auto carve_pack = [&](int K) -> u16* {
    return (u16*)carve((size_t)3 * HD * K * 2 * 2);
  };
  u16* pk_e0ih = carve_pack(DIN);
  u16* pk_e0hh = carve_pack(HD);
  u16* pk_e1ih = carve_pack(HD);
  u16* pk_e1hh = carve_pack(HD);
  u16* pk_d0hh = carve_pack(HD);
  u16* pk_d1ih = carve_pack(HD);
  u16* pk_d1hh = carve_pack(HD);

  hipMemsetAsync(h1aH, 0, (size_t)BB * HD * 2, stream);
  hipMemsetAsync(h1aL, 0, (size_t)BB * HD * 2, stream);
  hipMemsetAsync(h2aH, 0, (size_t)BB * HD * 2, stream);
  hipMemsetAsync(h2aL, 0, (size_t)BB * HD * 2, stream);

  auto pack = [&](const float* W, int K, u16* dst) {
    int total = 16 * (K >> 5) * 3 * 2 * 2 * 64;
    pack_w_kernel<<<(total + 255) / 256, 256, 0, stream>>>(W, K, dst);
  };
  pack(eW_ih0, DIN, pk_e0ih);
  pack(eW_hh0, HD, pk_e0hh);
  pack(eW_ih1, HD, pk_e1ih);
  pack(eW_hh1, HD, pk_e1hh);
  pack(dW_hh0, HD, pk_d0hh);
  pack(dW_ih1, HD, pk_d1ih);
  pack(dW_hh1, HD, pk_d1hh);

  u16 *h1cH = h1aH, *h1cL = h1aL, *h1nH = h1bH, *h1nL = h1bL;
  u16 *h2cH = h2aH, *h2cL = h2aL, *h2nH = h2bH, *h2nL = h2bL;
  auto swp = [](u16*& a, u16*& b) { u16* t = a; a = b; b = t; };

  for (int k = 0; k <= TT; ++k) {
    int mode = (k == 0) ? 0 : ((k == TT) ? 1 : 2);
    dim3 g(mode == 2 ? 64 : 32, 16);
    enc_phase_kernel<<<g, 256, 0, stream>>>(
        mode, k, x, pk_e0ih, pk_e0hh, eb_ih0, eb_hh0,
        pk_e1ih, pk_e1hh, eb_ih1, eb_hh1,
        h1cH, h1cL, h1nH, h1nL, h2cH, h2cL, h2nH, h2nL);
    if (k < TT) { swp(h1cH, h1nH); swp(h1cL, h1nL); }
    if (k > 0)  { swp(h2cH, h2nH); swp(h2cL, h2nL); }
  }

  for (int t = 0; t < PP; ++t) {
    dec_l0_kernel<<<dim3(32, 16), 256, 0, stream>>>(
        t, ypart, outb, dstart, dW_ih0, h1cH, h1cL, pk_d0hh,
        db_ih0, db_hh0, h1nH, h1nL, out);
    dec_l1_kernel<<<dim3(32, 16), 256, 0, stream>>>(
        h1nH, h1nL, pk_d1ih, h2cH, h2cL, pk_d1hh,
        db_ih1, db_hh1, h2nH, h2nL, outW, ypart);
    swp(h1cH, h1nH); swp(h1cL, h1nL);
    swp(h2cH, h2nH); swp(h2cL, h2nL);
  }
  finalize_y_kernel<<<4, 256, 0, stream>>>(ypart, outb, out);
}

// Round 3
// 27708.820 us; speedup vs baseline: 1.3640x; 1.1724x over previous
//
#include <hip/hip_runtime.h>

#define HD 512
#define BB 1024
#define TT 512
#define PP 96
#define DIN 32
#define KC_H (HD / 32)  // 16

typedef unsigned short u16;
typedef __attribute__((ext_vector_type(8))) short bf16x8;
typedef __attribute__((ext_vector_type(4))) float f32x4;
typedef __attribute__((address_space(3))) unsigned int lds_u32;
typedef __attribute__((address_space(1))) unsigned int glb_u32;

__device__ __forceinline__ float bf2f(u16 s) {
  return __uint_as_float(((unsigned)s) << 16);
}
__device__ __forceinline__ u16 f2bf_rne(float f) {
  unsigned u = __float_as_uint(f);
  u += 0x7FFF + ((u >> 16) & 1);
  return (u16)(u >> 16);
}
__device__ __forceinline__ float sigm(float v) { return 1.f / (1.f + __expf(-v)); }
__device__ __forceinline__ float tanh_(float a) {
  return 1.f - 2.f / (__expf(2.f * a) + 1.f);
}
__device__ __forceinline__ void split_store(u16* __restrict__ H, u16* __restrict__ L,
                                            size_t idx, float hv) {
  u16 hi = (u16)(__float_as_uint(hv) >> 16);  // trunc; lo corrects
  H[idx] = hi;
  L[idx] = f2bf_rne(hv - bf2f(hi));
}
__device__ __forceinline__ float plane_read(const u16* __restrict__ H,
                                            const u16* __restrict__ L, size_t idx) {
  return bf2f(H[idx]) + bf2f(L[idx]);
}

// Pack fp32 weight W[3H x K] into MFMA B-frag-linear bf16 hi/lo layout.
// u16 offset = ((((jb*KC + kc)*3 + g)*2 + s)*2 + fc)*512 + lane*8
// lane holds W[g*H + jb*32 + fc*16 + (lane&15)][kc*32 + (lane>>4)*8 + 0..7]
__global__ void pack_w_kernel(const float* __restrict__ W, int K,
                              u16* __restrict__ out) {
  int tid = blockIdx.x * 256 + threadIdx.x;
  int KC = K >> 5;
  int total = 16 * KC * 3 * 2 * 2 * 64;
  if (tid >= total) return;
  int lane = tid & 63;
  int rest = tid >> 6;
  int fc = rest & 1; rest >>= 1;
  int s  = rest & 1; rest >>= 1;
  int g  = rest % 3; rest /= 3;
  int kc = rest % KC;
  int jb = rest / KC;
  int j = jb * 32 + fc * 16 + (lane & 15);
  int k = kc * 32 + (lane >> 4) * 8;
  const float* src = W + (size_t)(g * HD + j) * K + k;
  bf16x8 v;
#pragma unroll
  for (int i = 0; i < 8; ++i) {
    float f = src[i];
    u16 hi = f2bf_rne(f);
    v[i] = (short)((s == 0) ? hi : f2bf_rne(f - bf2f(hi)));
  }
  *(bf16x8*)(out + (size_t)tid * 8) = v;
}

// A-fragment pair (hi/lo planes) for 2 row-subtiles.
struct AF {
  bf16x8 h[2];
  bf16x8 l[2];
};

__device__ __forceinline__ void load_af(AF& a, const u16* __restrict__ aH0,
                                        const u16* __restrict__ aL0, int kc) {
  const u16* p = aH0 + kc * 32;
  a.h[0] = *(const bf16x8*)p;
  a.h[1] = *(const bf16x8*)(p + 16 * HD);
  const u16* q = aL0 + kc * 32;
  a.l[0] = *(const bf16x8*)q;
  a.l[1] = *(const bf16x8*)(q + 16 * HD);
}

// 18 MFMAs for one kc: 3 gates x 2 row-subtiles x 3 split terms.
// wb points at a 6144-u16 kc-block (LDS or global); wave reads its fc half.
__device__ __forceinline__ void mfma_kc(const u16* __restrict__ wb, int fc, int lane,
                                        const AF& a, f32x4* __restrict__ aR,
                                        f32x4* __restrict__ aZ, f32x4* __restrict__ aN) {
  const u16* base = wb + fc * 512 + lane * 8;
#pragma unroll
  for (int g = 0; g < 3; ++g) {
    f32x4* acc = (g == 0) ? aR : (g == 1) ? aZ : aN;
    bf16x8 whi = *(const bf16x8*)(base + g * 2048);
    bf16x8 wlo = *(const bf16x8*)(base + g * 2048 + 1024);
#pragma unroll
    for (int s = 0; s < 2; ++s) {
      acc[s] = __builtin_amdgcn_mfma_f32_16x16x32_bf16(a.h[s], whi, acc[s], 0, 0, 0);
      acc[s] = __builtin_amdgcn_mfma_f32_16x16x32_bf16(a.l[s], whi, acc[s], 0, 0, 0);
      acc[s] = __builtin_amdgcn_mfma_f32_16x16x32_bf16(a.h[s], wlo, acc[s], 0, 0, 0);
    }
  }
}

// Stage one 6144-u16 (12KB) weight kc-chunk into LDS: 12 x 1KB DMA, 3 per wave.
__device__ __forceinline__ void stage_w(const u16* __restrict__ gsrc,
                                        u16* __restrict__ lbase, int wave, int lane) {
  const u16* g = gsrc + wave * 1536 + lane * 8;
  u16* l = lbase + wave * 1536;
#pragma unroll
  for (int j = 0; j < 3; ++j)
    __builtin_amdgcn_global_load_lds((const glb_u32*)(g + j * 512),
                                     (lds_u32*)(l + j * 512), 16, 0, 0);
}

// One full K=512 GEMM phase with LDS-staged weights (double-buffered) and
// register-double-buffered A fragments.
__device__ __forceinline__ void staged_phase(
    u16* __restrict__ wbuf,  // [2*6144] shared
    const u16* __restrict__ Ahi, const u16* __restrict__ Alo,
    const u16* __restrict__ Wjb,  // pack base + jb*16*6144
    int row0, int fc, int wave, int lane,
    f32x4* __restrict__ aR, f32x4* __restrict__ aZ, f32x4* __restrict__ aN) {
  const int quad = lane >> 4, n16 = lane & 15;
  const u16* aH0 = Ahi + (size_t)(row0 + n16) * HD + quad * 8;
  const u16* aL0 = Alo + (size_t)(row0 + n16) * HD + quad * 8;
  stage_w(Wjb, wbuf, wave, lane);
  AF a0, a1;
  load_af(a0, aH0, aL0, 0);
#pragma unroll 1
  for (int kc = 0; kc < KC_H; kc += 2) {
    __syncthreads();  // drains vmcnt -> stage(kc) + A(kc) visible
    stage_w(Wjb + (kc + 1) * 6144, wbuf + 6144, wave, lane);
    load_af(a1, aH0, aL0, kc + 1);
    mfma_kc(wbuf, fc, lane, a0, aR, aZ, aN);
    __syncthreads();
    if (kc + 2 < KC_H) {
      stage_w(Wjb + (kc + 2) * 6144, wbuf, wave, lane);
      load_af(a0, aH0, aL0, kc + 2);
    }
    mfma_kc(wbuf + 6144, fc, lane, a1, aR, aZ, aN);
  }
}

__device__ __forceinline__ void gru_epilogue(
    const float* __restrict__ bi, const float* __restrict__ bh,
    const u16* __restrict__ hcH, const u16* __restrict__ hcL,
    u16* __restrict__ hnH, u16* __restrict__ hnL,
    int jb, int fc, int row0, int quad, int n16,
    const f32x4* __restrict__ aR, const f32x4* __restrict__ aZ,
    const f32x4* __restrict__ aNX, const f32x4* __restrict__ aNH) {
  const int col = jb * 32 + fc * 16 + n16;
  const float bir = bi[col],          bhr = bh[col];
  const float biz = bi[HD + col],     bhz = bh[HD + col];
  const float bin = bi[2 * HD + col], bhn = bh[2 * HD + col];
#pragma unroll
  for (int s = 0; s < 2; ++s)
#pragma unroll
    for (int r = 0; r < 4; ++r) {
      const int row = row0 + s * 16 + quad * 4 + r;
      const size_t idx = (size_t)row * HD + col;
      float rr = sigm(aR[s][r] + bir + bhr);
      float zz = sigm(aZ[s][r] + biz + bhz);
      float nn = tanh_(aNX[s][r] + bin + rr * (aNH[s][r] + bhn));
      float ho = plane_read(hcH, hcL, idx);
      split_store(hnH, hnL, idx, (1.f - zz) * nn + zz * ho);
    }
}

// Skewed encoder phase. mode 0 = L0 only, 1 = L1 only, 2 = both
// (blockIdx.x < 16 -> L0 jb, >= 16 -> L1 jb-16).
__global__ __launch_bounds__(256, 2)
void enc_phase_kernel(int mode, int t, const float* __restrict__ x,
                      const u16* __restrict__ pkX0, const u16* __restrict__ pkH0,
                      const float* __restrict__ bi0, const float* __restrict__ bh0,
                      const u16* __restrict__ pkX1, const u16* __restrict__ pkH1,
                      const float* __restrict__ bi1, const float* __restrict__ bh1,
                      const u16* __restrict__ h1cH, const u16* __restrict__ h1cL,
                      u16* __restrict__ h1nH, u16* __restrict__ h1nL,
                      const u16* __restrict__ h2cH, const u16* __restrict__ h2cL,
                      u16* __restrict__ h2nH, u16* __restrict__ h2nL) {
  __shared__ u16 wbuf[2 * 6144];
  const int bx = blockIdx.x;
  int layer, jb;
  if (mode == 2) { layer = (bx >= 16) ? 1 : 0; jb = bx & 15; }
  else           { layer = mode;               jb = bx; }
  const int tid = threadIdx.x, wave = tid >> 6, lane = tid & 63;
  const int quad = lane >> 4, n16 = lane & 15;
  const int fc = wave & 1, rowg = wave >> 1;
  const int row0 = blockIdx.y * 64 + rowg * 32;

  const f32x4 z4 = {0.f, 0.f, 0.f, 0.f};
  f32x4 aR[2] = {z4, z4}, aZ[2] = {z4, z4}, aNX[2] = {z4, z4}, aNH[2] = {z4, z4};

  if (layer == 0) {
    // x-phase: K=32 (one kc), inline fp32->hi/lo split, weights from global (L2-hot)
    AF ax;
#pragma unroll
    for (int s = 0; s < 2; ++s) {
      const float* xp = x + (size_t)(row0 + s * 16 + n16) * (TT * DIN) +
                        (size_t)t * DIN + quad * 8;
      f32x4 v0 = *(const f32x4*)xp;
      f32x4 v1 = *(const f32x4*)(xp + 4);
      bf16x8 hi, lo;
#pragma unroll
      for (int i = 0; i < 8; ++i) {
        float f = (i < 4) ? v0[i] : v1[i - 4];
        u16 h = (u16)(__float_as_uint(f) >> 16);
        hi[i] = (short)h;
        lo[i] = (short)f2bf_rne(f - bf2f(h));
      }
      ax.h[s] = hi;
      ax.l[s] = lo;
    }
    mfma_kc(pkX0 + (size_t)jb * 6144, fc, lane, ax, aR, aZ, aNX);
    staged_phase(wbuf, h1cH, h1cL, pkH0 + (size_t)jb * KC_H * 6144,
                 row0, fc, wave, lane, aR, aZ, aNH);
    gru_epilogue(bi0, bh0, h1cH, h1cL, h1nH, h1nL, jb, fc, row0, quad, n16,
                 aR, aZ, aNX, aNH);
  } else {
    staged_phase(wbuf, h1cH, h1cL, pkX1 + (size_t)jb * KC_H * 6144,
                 row0, fc, wave, lane, aR, aZ, aNX);
    staged_phase(wbuf, h2cH, h2cL, pkH1 + (size_t)jb * KC_H * 6144,
                 row0, fc, wave, lane, aR, aZ, aNH);
    gru_epilogue(bi1, bh1, h2cH, h2cL, h2nH, h2nL, jb, fc, row0, quad, n16,
                 aR, aZ, aNX, aNH);
  }
}

// Decoder L0: h-phase GEMM + rank-1 gi from scalar y (summed from ypart[row][32]).
// Also writes y_{t-1} to dout.
__global__ __launch_bounds__(256, 2)
void dec_l0_kernel(int t, const float* __restrict__ ypart, const float* __restrict__ outb,
                   const float* __restrict__ dstart, const float* __restrict__ Wih0,
                   const u16* __restrict__ d1cH, const u16* __restrict__ d1cL,
                   const u16* __restrict__ pkHH,
                   const float* __restrict__ bih, const float* __restrict__ bhh,
                   u16* __restrict__ d1nH, u16* __restrict__ d1nL,
                   float* __restrict__ dout) {
  __shared__ u16 wbuf[2 * 6144];
  const int jb = blockIdx.x;
  const int tid = threadIdx.x, wave = tid >> 6, lane = tid & 63;
  const int quad = lane >> 4, n16 = lane & 15;
  const int fc = wave & 1, rowg = wave >> 1;
  const int row0 = blockIdx.y * 64 + rowg * 32;

  const f32x4 z4 = {0.f, 0.f, 0.f, 0.f};
  f32x4 aR[2] = {z4, z4}, aZ[2] = {z4, z4}, aNH[2] = {z4, z4};
  staged_phase(wbuf, d1cH, d1cL, pkHH + (size_t)jb * KC_H * 6144,
               row0, fc, wave, lane, aR, aZ, aNH);

  float yv[2][4];
#pragma unroll
  for (int s = 0; s < 2; ++s)
#pragma unroll
    for (int r = 0; r < 4; ++r) {
      const int row = row0 + s * 16 + quad * 4 + r;
      if (t == 0) {
        yv[s][r] = dstart[0];
      } else {
        const f32x4* yp = (const f32x4*)(ypart + (size_t)row * 32);
        f32x4 acc = yp[0];
#pragma unroll
        for (int i = 1; i < 8; ++i) {
          f32x4 v = yp[i];
          acc[0] += v[0]; acc[1] += v[1]; acc[2] += v[2]; acc[3] += v[3];
        }
        float sum = outb[0] + acc[0] + acc[1] + acc[2] + acc[3];
        yv[s][r] = sum;
        if (jb == 0 && fc == 0 && n16 == 0)
          dout[(size_t)row * PP + (t - 1)] = sum;
      }
    }

  const int col = jb * 32 + fc * 16 + n16;
  const float bir = bih[col],          bhr = bhh[col];
  const float biz = bih[HD + col],     bhz = bhh[HD + col];
  const float bin = bih[2 * HD + col], bhn = bhh[2 * HD + col];
  const float w0r = Wih0[col], w0z = Wih0[HD + col], w0n = Wih0[2 * HD + col];
#pragma unroll
  for (int s = 0; s < 2; ++s)
#pragma unroll
    for (int r = 0; r < 4; ++r) {
      const int row = row0 + s * 16 + quad * 4 + r;
      const size_t idx = (size_t)row * HD + col;
      float rr = sigm(aR[s][r] + bir + bhr + yv[s][r] * w0r);
      float zz = sigm(aZ[s][r] + biz + bhz + yv[s][r] * w0z);
      float nn = tanh_(bin + yv[s][r] * w0n + rr * (aNH[s][r] + bhn));
      float ho = plane_read(d1cH, d1cL, idx);
      split_store(d1nH, d1nL, idx, (1.f - zz) * nn + zz * ho);
    }
}

// Decoder L1: x-phase (d1 new) + h-phase (d2); emits ypart[row][32] partial dots.
__global__ __launch_bounds__(256, 2)
void dec_l1_kernel(const u16* __restrict__ xH, const u16* __restrict__ xL,
                   const u16* __restrict__ pkIH,
                   const u16* __restrict__ d2cH, const u16* __restrict__ d2cL,
                   const u16* __restrict__ pkHH,
                   const float* __restrict__ bih, const float* __restrict__ bhh,
                   u16* __restrict__ d2nH, u16* __restrict__ d2nL,
                   const float* __restrict__ outW, float* __restrict__ ypart) {
  __shared__ u16 wbuf[2 * 6144];
  const int jb = blockIdx.x;
  const int tid = threadIdx.x, wave = tid >> 6, lane = tid & 63;
  const int quad = lane >> 4, n16 = lane & 15;
  const int fc = wave & 1, rowg = wave >> 1;
  const int row0 = blockIdx.y * 64 + rowg * 32;

  const f32x4 z4 = {0.f, 0.f, 0.f, 0.f};
  f32x4 aR[2] = {z4, z4}, aZ[2] = {z4, z4}, aNX[2] = {z4, z4}, aNH[2] = {z4, z4};
  staged_phase(wbuf, xH, xL, pkIH + (size_t)jb * KC_H * 6144,
               row0, fc, wave, lane, aR, aZ, aNX);
  staged_phase(wbuf, d2cH, d2cL, pkHH + (size_t)jb * KC_H * 6144,
               row0, fc, wave, lane, aR, aZ, aNH);

  const int col = jb * 32 + fc * 16 + n16;
  const float bir = bih[col],          bhr = bhh[col];
  const float biz = bih[HD + col],     bhz = bhh[HD + col];
  const float bin = bih[2 * HD + col], bhn = bhh[2 * HD + col];
  const float wo = outW[col];
#pragma unroll
  for (int s = 0; s < 2; ++s)
#pragma unroll
    for (int r = 0; r < 4; ++r) {
      const int row = row0 + s * 16 + quad * 4 + r;
      const size_t idx = (size_t)row * HD + col;
      float rr = sigm(aR[s][r] + bir + bhr);
      float zz = sigm(aZ[s][r] + biz + bhz);
      float nn = tanh_(aNX[s][r] + bin + rr * (aNH[s][r] + bhn));
      float ho = plane_read(d2cH, d2cL, idx);
      float hv = (1.f - zz) * nn + zz * ho;
      split_store(d2nH, d2nL, idx, hv);
      float v = hv * wo;
#pragma unroll
      for (int off = 1; off < 16; off <<= 1) v += __shfl_xor(v, off, 16);
      if (n16 == 0) ypart[(size_t)row * 32 + jb * 2 + fc] = v;
    }
}

__global__ void finalize_y_kernel(const float* __restrict__ ypart,
                                  const float* __restrict__ outb,
                                  float* __restrict__ dout) {
  int b = blockIdx.x * 256 + threadIdx.x;
  if (b >= BB) return;
  const f32x4* yp = (const f32x4*)(ypart + (size_t)b * 32);
  f32x4 acc = yp[0];
#pragma unroll
  for (int i = 1; i < 8; ++i) {
    f32x4 v = yp[i];
    acc[0] += v[0]; acc[1] += v[1]; acc[2] += v[2]; acc[3] += v[3];
  }
  dout[(size_t)b * PP + (PP - 1)] = outb[0] + acc[0] + acc[1] + acc[2] + acc[3];
}

extern "C" void kernel_launch(void* const* d_in, const int* in_sizes, int n_in,
                              void* d_out, int out_size, void* d_ws, size_t ws_size,
                              hipStream_t stream) {
  const float* x      = (const float*)d_in[0];
  const float* eW_ih0 = (const float*)d_in[1];
  const float* eW_hh0 = (const float*)d_in[2];
  const float* eb_ih0 = (const float*)d_in[3];
  const float* eb_hh0 = (const float*)d_in[4];
  const float* eW_ih1 = (const float*)d_in[5];
  const float* eW_hh1 = (const float*)d_in[6];
  const float* eb_ih1 = (const float*)d_in[7];
  const float* eb_hh1 = (const float*)d_in[8];
  const float* dW_ih0 = (const float*)d_in[9];
  const float* dW_hh0 = (const float*)d_in[10];
  const float* db_ih0 = (const float*)d_in[11];
  const float* db_hh0 = (const float*)d_in[12];
  const float* dW_ih1 = (const float*)d_in[13];
  const float* dW_hh1 = (const float*)d_in[14];
  const float* db_ih1 = (const float*)d_in[15];
  const float* db_hh1 = (const float*)d_in[16];
  const float* outW   = (const float*)d_in[17];
  const float* outb   = (const float*)d_in[18];
  const float* dstart = (const float*)d_in[19];
  float* out = (float*)d_out;

  char* w = (char*)d_ws;
  size_t off = 0;
  auto carve = [&](size_t bytes) -> void* {
    void* p = w + off;
    off = (off + bytes + 255) & ~(size_t)255;
    return p;
  };
  u16* h1aH = (u16*)carve((size_t)BB * HD * 2); u16* h1aL = (u16*)carve((size_t)BB * HD * 2);
  u16* h1bH = (u16*)carve((size_t)BB * HD * 2); u16* h1bL = (u16*)carve((size_t)BB * HD * 2);
  u16* h2aH = (u16*)carve((size_t)BB * HD * 2); u16* h2aL = (u16*)carve((size_t)BB * HD * 2);
  u16* h2bH = (u16*)carve((size_t)BB * HD * 2); u16* h2bL = (u16*)carve((size_t)BB * HD * 2);
  float* ypart = (float*)carve((size_t)BB * 32 * 4);
  auto carve_pack = [&](int K) -> u16* {
    return (u16*)carve((size_t)3 * HD * K * 2 * 2);
  };
  u16* pk_e0ih = carve_pack(DIN);
  u16* pk_e0hh = carve_pack(HD);
  u16* pk_e1ih = carve_pack(HD);
  u16* pk_e1hh = carve_pack(HD);
  u16* pk_d0hh = carve_pack(HD);
  u16* pk_d1ih = carve_pack(HD);
  u16* pk_d1hh = carve_pack(HD);

  hipMemsetAsync(h1aH, 0, (size_t)BB * HD * 2, stream);
  hipMemsetAsync(h1aL, 0, (size_t)BB * HD * 2, stream);
  hipMemsetAsync(h2aH, 0, (size_t)BB * HD * 2, stream);
  hipMemsetAsync(h2aL, 0, (size_t)BB * HD * 2, stream);

  auto pack = [&](const float* W, int K, u16* dst) {
    int total = 16 * (K >> 5) * 3 * 2 * 2 * 64;
    pack_w_kernel<<<(total + 255) / 256, 256, 0, stream>>>(W, K, dst);
  };
  pack(eW_ih0, DIN, pk_e0ih);
  pack(eW_hh0, HD, pk_e0hh);
  pack(eW_ih1, HD, pk_e1ih);
  pack(eW_hh1, HD, pk_e1hh);
  pack(dW_hh0, HD, pk_d0hh);
  pack(dW_ih1, HD, pk_d1ih);
  pack(dW_hh1, HD, pk_d1hh);

  u16 *h1cH = h1aH, *h1cL = h1aL, *h1nH = h1bH, *h1nL = h1bL;
  u16 *h2cH = h2aH, *h2cL = h2aL, *h2nH = h2bH, *h2nL = h2bL;
  auto swp = [](u16*& a, u16*& b) { u16* t = a; a = b; b = t; };

  for (int k = 0; k <= TT; ++k) {
    int mode = (k == 0) ? 0 : ((k == TT) ? 1 : 2);
    dim3 g(mode == 2 ? 32 : 16, 16);
    enc_phase_kernel<<<g, 256, 0, stream>>>(
        mode, k, x, pk_e0ih, pk_e0hh, eb_ih0, eb_hh0,
        pk_e1ih, pk_e1hh, eb_ih1, eb_hh1,
        h1cH, h1cL, h1nH, h1nL, h2cH, h2cL, h2nH, h2nL);
    if (k < TT) { swp(h1cH, h1nH); swp(h1cL, h1nL); }
    if (k > 0)  { swp(h2cH, h2nH); swp(h2cL, h2nL); }
  }

  for (int t = 0; t < PP; ++t) {
    dec_l0_kernel<<<dim3(16, 16), 256, 0, stream>>>(
        t, ypart, outb, dstart, dW_ih0, h1cH, h1cL, pk_d0hh,
        db_ih0, db_hh0, h1nH, h1nL, out);
    dec_l1_kernel<<<dim3(16, 16), 256, 0, stream>>>(
        h1nH, h1nL, pk_d1ih, h2cH, h2cL, pk_d1hh,
        db_ih1, db_hh1, h2nH, h2nL, outW, ypart);
    swp(h1cH, h1nH); swp(h1cL, h1nL);
    swp(h2cH, h2nH); swp(h2cL, h2nL);
  }
  finalize_y_kernel<<<4, 256, 0, stream>>>(ypart, outb, out);
}